// Round 5
// baseline (433.239 us; speedup 1.0000x reference)
//
#include <hip/hip_runtime.h>
#include <hip/hip_bf16.h>
#include <math.h>

// Problem constants (fixed shapes from setup_inputs)
#define B_    2
#define N_    2048
#define D_    1024
#define H_    16
#define ENC_  8
#define HD_   64
#define EPS_  1e-5f
#define M_    (B_ * N_)        // 4096 rows for all GEMMs

typedef __bf16 bf16x8 __attribute__((ext_vector_type(8)));
typedef float  f32x4  __attribute__((ext_vector_type(4)));

#define MB(x) ((size_t)(x) * 1024 * 1024)

// Async global->LDS 16B copy. HW writes lds_base + lane*16; lds ptr must be
// wave-uniform and the lane->global mapping must match that contiguity.
__device__ __forceinline__ void gld16(const __bf16* g, __bf16* l) {
    __builtin_amdgcn_global_load_lds(
        (const __attribute__((address_space(1))) void*)g,
        (__attribute__((address_space(3))) void*)l,
        16, 0, 0);
}

// ---------------------------------------------------------------------------
// bf16 MFMA GEMM, B pre-transposed: C[M,Nn] = A[M,K] @ Bt[Nn,K]^T.
// m97 structure: 128x128 tile, BK=32, 4 waves (2x2), each wave 4x4 MFMA
// 16x16x32 tiles, global_load_lds width-16 staging, 2-barrier K-loop.
// ---------------------------------------------------------------------------
template <typename OutT>
__global__ __launch_bounds__(256) void gemm_bt(
    const __bf16* __restrict__ A, const __bf16* __restrict__ Bt,
    OutT* __restrict__ C, int K, int lda, int aoff, int ldc)
{
    __shared__ __bf16 As[128 * 32];   // [row][k], 64 B rows
    __shared__ __bf16 Bs[128 * 32];   // [col][k]

    const int tid  = threadIdx.x;
    const int w    = tid >> 6;
    const int lane = tid & 63;
    const int lrow = lane & 15;
    const int quad = lane >> 4;
    const int wr   = w >> 1;           // wave row 0..1
    const int wc   = w & 1;            // wave col 0..1

    const int bm = blockIdx.y * 128;
    const int bn = blockIdx.x * 128;

    const int sr = lane >> 2;
    const int sc = (lane & 3) * 8;
    const __bf16* Ag0 = A  + (size_t)(bm +      w * 16 + sr) * lda + aoff + sc;
    const __bf16* Ag1 = A  + (size_t)(bm + 64 + w * 16 + sr) * lda + aoff + sc;
    const __bf16* Bg0 = Bt + (size_t)(bn +      w * 16 + sr) * K + sc;
    const __bf16* Bg1 = Bt + (size_t)(bn + 64 + w * 16 + sr) * K + sc;
    __bf16* Al0 = &As[w * 512];
    __bf16* Al1 = &As[2048 + w * 512];
    __bf16* Bl0 = &Bs[w * 512];
    __bf16* Bl1 = &Bs[2048 + w * 512];

    f32x4 acc[4][4];
    #pragma unroll
    for (int i = 0; i < 4; ++i)
        #pragma unroll
        for (int j = 0; j < 4; ++j) acc[i][j] = (f32x4){0.f, 0.f, 0.f, 0.f};

    for (int k0 = 0; k0 < K; k0 += 32) {
        gld16(Ag0 + k0, Al0);
        gld16(Ag1 + k0, Al1);
        gld16(Bg0 + k0, Bl0);
        gld16(Bg1 + k0, Bl1);
        __syncthreads();   // drains vmcnt -> LDS data visible

        bf16x8 af[4], bf[4];
        #pragma unroll
        for (int rt = 0; rt < 4; ++rt)
            af[rt] = *(const bf16x8*)&As[(wr * 64 + rt * 16 + lrow) * 32 + quad * 8];
        #pragma unroll
        for (int ct = 0; ct < 4; ++ct)
            bf[ct] = *(const bf16x8*)&Bs[(wc * 64 + ct * 16 + lrow) * 32 + quad * 8];

        #pragma unroll
        for (int rt = 0; rt < 4; ++rt)
            #pragma unroll
            for (int ct = 0; ct < 4; ++ct)
                acc[rt][ct] = __builtin_amdgcn_mfma_f32_16x16x32_bf16(
                    af[rt], bf[ct], acc[rt][ct], 0, 0, 0);
        __syncthreads();
    }

    #pragma unroll
    for (int rt = 0; rt < 4; ++rt)
        #pragma unroll
        for (int ct = 0; ct < 4; ++ct)
            #pragma unroll
            for (int r = 0; r < 4; ++r) {
                const int row = bm + wr * 64 + rt * 16 + quad * 4 + r;
                const int col = bn + wc * 64 + ct * 16 + lrow;
                C[(size_t)row * ldc + col] = (OutT)acc[rt][ct][r];
            }
}

// ---------------------------------------------------------------------------
__global__ __launch_bounds__(256) void f32_to_bf16(
    const float* __restrict__ src, __bf16* __restrict__ dst)
{
    const size_t i = ((size_t)blockIdx.x * 256 + threadIdx.x) * 8;
    float4 a = *(const float4*)&src[i];
    float4 b = *(const float4*)&src[i + 4];
    bf16x8 o = {(__bf16)a.x, (__bf16)a.y, (__bf16)a.z, (__bf16)a.w,
                (__bf16)b.x, (__bf16)b.y, (__bf16)b.z, (__bf16)b.w};
    *(bf16x8*)&dst[i] = o;
}

// ---------------------------------------------------------------------------
// Weight convert + transpose: W[K,Nn] fp32 -> Wt[Nn,K] bf16. 64x64 LDS tiles.
// ---------------------------------------------------------------------------
__global__ __launch_bounds__(256) void wt_conv(
    const float* __restrict__ W, __bf16* __restrict__ Wt, int K, int Nn)
{
    __shared__ __bf16 t[64][72];
    const int kb = blockIdx.y * 64;
    const int nb = blockIdx.x * 64;
    {
        const int kl = threadIdx.x >> 2;
        const int c0 = (threadIdx.x & 3) * 16;
        const float* src = W + (size_t)(kb + kl) * Nn + nb + c0;
        #pragma unroll
        for (int u = 0; u < 4; ++u) {
            float4 f = *(const float4*)&src[u * 4];
            t[c0 + u * 4 + 0][kl] = (__bf16)f.x;
            t[c0 + u * 4 + 1][kl] = (__bf16)f.y;
            t[c0 + u * 4 + 2][kl] = (__bf16)f.z;
            t[c0 + u * 4 + 3][kl] = (__bf16)f.w;
        }
    }
    __syncthreads();
    {
        const int nl  = threadIdx.x >> 2;
        const int k0c = (threadIdx.x & 3) * 16;
        __bf16* dst = Wt + (size_t)(nb + nl) * K + kb + k0c;
        *(bf16x8*)&dst[0] = *(const bf16x8*)&t[nl][k0c];
        *(bf16x8*)&dst[8] = *(const bf16x8*)&t[nl][k0c + 8];
    }
}

// ---------------------------------------------------------------------------
// Fused RoPE + RMSNorm. Reads bf16 fused qkv [4096][3072] (q col 0, k col
// 1024), writes bf16 head-major (B,H,N,HD). One wave per row.
// ---------------------------------------------------------------------------
__global__ __launch_bounds__(256) void rope_rms_bf(
    const __bf16* __restrict__ qkv,
    const float* __restrict__ cs, const float* __restrict__ sn,
    __bf16* __restrict__ qbf, __bf16* __restrict__ kbf)
{
    const int row  = blockIdx.x * 4 + (threadIdx.x >> 6);  // (b*N + n)*H + h
    const int lane = threadIdx.x & 63;
    const int n    = (row >> 4) & (N_ - 1);
    const int b    = row >> 15;
    const int h    = row & 15;
    const int p    = lane >> 1;

    const float c = cs[n * (HD_ / 2) + p];
    const float s = sn[n * (HD_ / 2) + p];
    const size_t ibase = (size_t)(b * N_ + n) * 3072 + h * HD_ + lane;
    const size_t obase = ((size_t)(b * H_ + h) * N_ + n) * HD_ + lane;
    const bool odd = (lane & 1);

    {
        float val = (float)qkv[ibase];                  // q
        float partner = __shfl_xor(val, 1, 64);
        float r = odd ? fmaf(partner, s, val * c)
                      : (val * c - partner * s);
        float ss = r * r;
        #pragma unroll
        for (int off = 1; off < 64; off <<= 1) ss += __shfl_xor(ss, off, 64);
        qbf[obase] = (__bf16)(r * rsqrtf(ss * (1.0f / 64.0f) + EPS_));
    }
    {
        float val = (float)qkv[ibase + 1024];           // k
        float partner = __shfl_xor(val, 1, 64);
        float r = odd ? fmaf(partner, s, val * c)
                      : (val * c - partner * s);
        float ss = r * r;
        #pragma unroll
        for (int off = 1; off < 64; off <<= 1) ss += __shfl_xor(ss, off, 64);
        kbf[obase] = (__bf16)(r * rsqrtf(ss * (1.0f / 64.0f) + EPS_));
    }
}

// ---------------------------------------------------------------------------
// V transpose: bf16 v slice of qkv (cols 2048..3071) -> bf16 (B,H,HD,N).
// ---------------------------------------------------------------------------
__global__ __launch_bounds__(256) void vconv(
    const __bf16* __restrict__ qkv, __bf16* __restrict__ vt)
{
    __shared__ __bf16 tile[64][72];
    const int bh = blockIdx.y;
    const int b  = bh >> 4, h = bh & 15;
    const int n0 = blockIdx.x * 64;
    {
        const int nl = threadIdx.x >> 2;
        const int d0 = (threadIdx.x & 3) * 16;
        const __bf16* src = qkv + (size_t)(b * N_ + n0 + nl) * 3072 + 2048 + h * HD_ + d0;
        bf16x8 v0 = *(const bf16x8*)&src[0];
        bf16x8 v1 = *(const bf16x8*)&src[8];
        #pragma unroll
        for (int e = 0; e < 8; ++e) {
            tile[d0 + e][nl]     = v0[e];
            tile[d0 + 8 + e][nl] = v1[e];
        }
    }
    __syncthreads();
    {
        const int dl = threadIdx.x >> 2;
        const int nc = (threadIdx.x & 3) * 16;
        __bf16* dst = vt + ((size_t)(bh * HD_ + dl)) * N_ + n0 + nc;
        *(bf16x8*)&dst[0] = *(const bf16x8*)&tile[dl][nc];
        *(bf16x8*)&dst[8] = *(const bf16x8*)&tile[dl][nc + 8];
    }
}

// ---------------------------------------------------------------------------
// MFMA flash attention v3 (bf16 in, bf16 out).
// R5 changes vs R4: occupancy-first.
//  - wave = 16 q-rows (1 MFMA q-tile), block = 4 waves = 64 q-rows
//    -> grid 32x32 = 1024 blocks, 4096 waves (2x TLP of R4)
//  - no register double-buffer (R4 measured neutral; VGPRs -> occupancy)
//  - heavy-blocks-first: q-block index reversed so deep causal/enc tiles
//    launch first (shorter tail)
//  - Plds rows padded to 36 (kept from R4: conflict-free)
//  - causal mask only on a dec wave's last tile (wave-uniform branch)
// ---------------------------------------------------------------------------
__global__ __launch_bounds__(256) void attn_mfma(
    const __bf16* __restrict__ qbf, const __bf16* __restrict__ kbf,
    const __bf16* __restrict__ vtbf, __bf16* __restrict__ o)
{
    __shared__ __bf16 Plds[4][16][36];   // [wave][qrow][key(padded)]

    const int w    = threadIdx.x >> 6;
    const int lane = threadIdx.x & 63;
    const int lrow = lane & 15;
    const int quad = lane >> 4;

    const int bh = blockIdx.x;                       // 0..31
    const int qb = gridDim.y - 1 - blockIdx.y;       // heavy-first
    const int b  = bh >> 4, h = bh & 15;
    const bool enc = (h < ENC_);
    const int i0 = qb * 64 + w * 16;                 // wave's 16 q-rows

    const __bf16* qbase = qbf  + (size_t)bh * N_ * HD_;
    const __bf16* kbase = kbf  + (size_t)bh * N_ * HD_;
    const __bf16* vbase = vtbf + (size_t)bh * HD_ * N_;

    bf16x8 qf[2];
    #pragma unroll
    for (int kc = 0; kc < 2; ++kc)
        qf[kc] = *(const bf16x8*)
            &qbase[(size_t)(i0 + lrow) * HD_ + kc * 32 + quad * 8];

    const f32x4 zero = {0.f, 0.f, 0.f, 0.f};
    f32x4 oacc[4];
    #pragma unroll
    for (int c = 0; c < 4; ++c) oacc[c] = zero;
    float lsum[4] = {};

    const float KS = 0.125f * 1.4426950408889634f;
    const float KO = -8.0f  * 1.4426950408889634f;

    // keys allowed: enc -> all N; dec -> j <= i0+15, tiles cover [0, i0+16)
    const int ntiles = enc ? (N_ >> 5) : ((i0 + 16 + 31) >> 5);
    const bool dec = !enc;

    const __bf16* kptr = kbase + (size_t)lrow * HD_ + quad * 8;
    const __bf16* vptr = vbase + (size_t)lrow * N_ + quad * 8;

    for (int t = 0; t < ntiles; ++t) {
        const int j0 = t << 5;

        // K fragments (2 key-subtiles x 2 k-chunks) + V fragments (4 dim-chunks)
        const __bf16* kp = kptr + (size_t)j0 * HD_;
        bf16x8 kf0 = *(const bf16x8*)(kp);
        bf16x8 kf1 = *(const bf16x8*)(kp + 32);
        bf16x8 kf2 = *(const bf16x8*)(kp + 16 * HD_);
        bf16x8 kf3 = *(const bf16x8*)(kp + 16 * HD_ + 32);
        const __bf16* vp = vptr + j0;
        bf16x8 vf0 = *(const bf16x8*)(vp);
        bf16x8 vf1 = *(const bf16x8*)(vp + 16 * N_);
        bf16x8 vf2 = *(const bf16x8*)(vp + 32 * N_);
        bf16x8 vf3 = *(const bf16x8*)(vp + 48 * N_);

        f32x4 s0 = zero, s1 = zero;
        s0 = __builtin_amdgcn_mfma_f32_16x16x32_bf16(qf[0], kf0, s0, 0, 0, 0);
        s0 = __builtin_amdgcn_mfma_f32_16x16x32_bf16(qf[1], kf1, s0, 0, 0, 0);
        s1 = __builtin_amdgcn_mfma_f32_16x16x32_bf16(qf[0], kf2, s1, 0, 0, 0);
        s1 = __builtin_amdgcn_mfma_f32_16x16x32_bf16(qf[1], kf3, s1, 0, 0, 0);

        if (dec && t == ntiles - 1) {
            #pragma unroll
            for (int r = 0; r < 4; ++r) {
                const int i  = i0 + quad * 4 + r;
                float pA = (j0 + lrow      <= i) ? exp2f(fmaf(s0[r], KS, KO)) : 0.f;
                float pB = (j0 + 16 + lrow <= i) ? exp2f(fmaf(s1[r], KS, KO)) : 0.f;
                lsum[r] += pA + pB;
                Plds[w][quad * 4 + r][lrow]      = (__bf16)pA;
                Plds[w][quad * 4 + r][lrow + 16] = (__bf16)pB;
            }
        } else {
            #pragma unroll
            for (int r = 0; r < 4; ++r) {
                float pA = exp2f(fmaf(s0[r], KS, KO));
                float pB = exp2f(fmaf(s1[r], KS, KO));
                lsum[r] += pA + pB;
                Plds[w][quad * 4 + r][lrow]      = (__bf16)pA;
                Plds[w][quad * 4 + r][lrow + 16] = (__bf16)pB;
            }
        }

        bf16x8 pf = *(const bf16x8*)&Plds[w][lrow][quad * 8];
        oacc[0] = __builtin_amdgcn_mfma_f32_16x16x32_bf16(pf, vf0, oacc[0], 0, 0, 0);
        oacc[1] = __builtin_amdgcn_mfma_f32_16x16x32_bf16(pf, vf1, oacc[1], 0, 0, 0);
        oacc[2] = __builtin_amdgcn_mfma_f32_16x16x32_bf16(pf, vf2, oacc[2], 0, 0, 0);
        oacc[3] = __builtin_amdgcn_mfma_f32_16x16x32_bf16(pf, vf3, oacc[3], 0, 0, 0);
    }

    #pragma unroll
    for (int r = 0; r < 4; ++r) {
        float s = lsum[r];
        s += __shfl_xor(s, 1, 64);
        s += __shfl_xor(s, 2, 64);
        s += __shfl_xor(s, 4, 64);
        s += __shfl_xor(s, 8, 64);
        lsum[r] = 1.0f / s;
    }

    // O (bf16, [4096][1024], col = h*64 + dim); C-layout row=quad*4+r
    #pragma unroll
    for (int c = 0; c < 4; ++c)
        #pragma unroll
        for (int r = 0; r < 4; ++r) {
            const int i = i0 + quad * 4 + r;
            o[(size_t)(b * N_ + i) * D_ + h * HD_ + c * 16 + lrow] =
                (__bf16)(oacc[c][r] * lsum[r]);
        }
}

// ---------------------------------------------------------------------------
extern "C" void kernel_launch(void* const* d_in, const int* in_sizes, int n_in,
                              void* d_out, int out_size, void* d_ws, size_t ws_size,
                              hipStream_t stream)
{
    const float* x   = (const float*)d_in[0];
    const float* cs  = (const float*)d_in[1];
    const float* sn  = (const float*)d_in[2];
    const float* Wq  = (const float*)d_in[3];
    const float* Wk  = (const float*)d_in[4];
    const float* Wv  = (const float*)d_in[5];
    const float* Woe = (const float*)d_in[6];
    const float* Wod = (const float*)d_in[7];

    float* enc_out = (float*)d_out;
    float* dec_out = enc_out + (size_t)M_ * D_;

    // Workspace (57 MB), stream-ordered aliasing:
    //   [0,8)    xbf      -> reused as vtbf after QKV GEMM
    //   [8,14)   wqkv_t   (3072 x 1024 bf16)
    //   [14,16)  woe_t    (1024 x 1024 bf16)
    //   [16,17)  wod_t    (1024 x 512 bf16)
    //   [17,41)  qkv      (4096 x 3072 bf16) -> reused as obuf
    //   [41,49)  qbf head-major
    //   [49,57)  kbf head-major
    char* ws = (char*)d_ws;
    __bf16* xbf    = (__bf16*)(ws);
    __bf16* wqkv_t = (__bf16*)(ws + MB(8));
    __bf16* woe_t  = (__bf16*)(ws + MB(14));
    __bf16* wod_t  = (__bf16*)(ws + MB(16));
    __bf16* qkv    = (__bf16*)(ws + MB(17));
    __bf16* qbf    = (__bf16*)(ws + MB(41));
    __bf16* kbf    = (__bf16*)(ws + MB(49));
    __bf16* vtbf   = xbf;     // xbf dead after QKV GEMM
    __bf16* obuf   = qkv;     // qkv dead after rope_rms_bf + vconv

    f32_to_bf16<<<(M_ * D_) / (256 * 8), 256, 0, stream>>>(x, xbf);
    wt_conv<<<dim3(16, 16), 256, 0, stream>>>(Wq, wqkv_t,                   D_, D_);
    wt_conv<<<dim3(16, 16), 256, 0, stream>>>(Wk, wqkv_t + 1024 * 1024,     D_, D_);
    wt_conv<<<dim3(16, 16), 256, 0, stream>>>(Wv, wqkv_t + 2 * 1024 * 1024, D_, D_);
    wt_conv<<<dim3(16, 16), 256, 0, stream>>>(Woe, woe_t, D_, D_);
    wt_conv<<<dim3(16, 8),  256, 0, stream>>>(Wod, wod_t, 512, D_);

    gemm_bt<__bf16><<<dim3(3072 / 128, M_ / 128), 256, 0, stream>>>(
        xbf, wqkv_t, qkv, D_, D_, 0, 3072);

    rope_rms_bf<<<(B_ * N_ * H_) / 4, 256, 0, stream>>>(qkv, cs, sn, qbf, kbf);
    vconv<<<dim3(N_ / 64, B_ * H_), 256, 0, stream>>>(qkv, vtbf);

    // 32 bh x 32 q-blocks (reversed inside kernel: heavy first)
    attn_mfma<<<dim3(B_ * H_, N_ / 64), 256, 0, stream>>>(qbf, kbf, vtbf, obuf);

    gemm_bt<float><<<dim3(D_ / 128, M_ / 128), 256, 0, stream>>>(
        obuf, woe_t, enc_out, D_, D_, 0, D_);
    gemm_bt<float><<<dim3(D_ / 128, M_ / 128), 256, 0, stream>>>(
        obuf, wod_t, dec_out, 512, D_, 512, D_);
}

// Round 7
// 291.773 us; speedup vs baseline: 1.4849x; 1.4849x over previous
//
#include <hip/hip_runtime.h>
#include <hip/hip_bf16.h>
#include <math.h>

// Problem constants (fixed shapes from setup_inputs)
#define B_    2
#define N_    2048
#define D_    1024
#define H_    16
#define ENC_  8
#define HD_   64
#define EPS_  1e-5f
#define M_    (B_ * N_)        // 4096 rows for all GEMMs

typedef __bf16 bf16x8 __attribute__((ext_vector_type(8)));
typedef float  f32x4  __attribute__((ext_vector_type(4)));

#define MB(x) ((size_t)(x) * 1024 * 1024)

// Async global->LDS 16B copy. HW writes lds_base + lane*16 (wave-uniform LDS
// base); the GLOBAL address is per-lane, so scattered gathers are fine.
__device__ __forceinline__ void gld16(const __bf16* g, __bf16* l) {
    __builtin_amdgcn_global_load_lds(
        (const __attribute__((address_space(1))) void*)g,
        (__attribute__((address_space(3))) void*)l,
        16, 0, 0);
}

// ---------------------------------------------------------------------------
// bf16 MFMA GEMM, B pre-transposed: C[M,Nn] = A[M,K] @ Bt[Nn,K]^T.
// m97 structure: 128x128 tile, BK=32, 4 waves (2x2), each wave 4x4 MFMA
// 16x16x32 tiles, global_load_lds width-16 staging, 2-barrier K-loop.
// ---------------------------------------------------------------------------
template <typename OutT>
__global__ __launch_bounds__(256) void gemm_bt(
    const __bf16* __restrict__ A, const __bf16* __restrict__ Bt,
    OutT* __restrict__ C, int K, int lda, int aoff, int ldc)
{
    __shared__ __bf16 As[128 * 32];   // [row][k], 64 B rows
    __shared__ __bf16 Bs[128 * 32];   // [col][k]

    const int tid  = threadIdx.x;
    const int w    = tid >> 6;
    const int lane = tid & 63;
    const int lrow = lane & 15;
    const int quad = lane >> 4;
    const int wr   = w >> 1;           // wave row 0..1
    const int wc   = w & 1;            // wave col 0..1

    const int bm = blockIdx.y * 128;
    const int bn = blockIdx.x * 128;

    const int sr = lane >> 2;
    const int sc = (lane & 3) * 8;
    const __bf16* Ag0 = A  + (size_t)(bm +      w * 16 + sr) * lda + aoff + sc;
    const __bf16* Ag1 = A  + (size_t)(bm + 64 + w * 16 + sr) * lda + aoff + sc;
    const __bf16* Bg0 = Bt + (size_t)(bn +      w * 16 + sr) * K + sc;
    const __bf16* Bg1 = Bt + (size_t)(bn + 64 + w * 16 + sr) * K + sc;
    __bf16* Al0 = &As[w * 512];
    __bf16* Al1 = &As[2048 + w * 512];
    __bf16* Bl0 = &Bs[w * 512];
    __bf16* Bl1 = &Bs[2048 + w * 512];

    f32x4 acc[4][4];
    #pragma unroll
    for (int i = 0; i < 4; ++i)
        #pragma unroll
        for (int j = 0; j < 4; ++j) acc[i][j] = (f32x4){0.f, 0.f, 0.f, 0.f};

    for (int k0 = 0; k0 < K; k0 += 32) {
        gld16(Ag0 + k0, Al0);
        gld16(Ag1 + k0, Al1);
        gld16(Bg0 + k0, Bl0);
        gld16(Bg1 + k0, Bl1);
        __syncthreads();   // drains vmcnt -> LDS data visible

        bf16x8 af[4], bf[4];
        #pragma unroll
        for (int rt = 0; rt < 4; ++rt)
            af[rt] = *(const bf16x8*)&As[(wr * 64 + rt * 16 + lrow) * 32 + quad * 8];
        #pragma unroll
        for (int ct = 0; ct < 4; ++ct)
            bf[ct] = *(const bf16x8*)&Bs[(wc * 64 + ct * 16 + lrow) * 32 + quad * 8];

        #pragma unroll
        for (int rt = 0; rt < 4; ++rt)
            #pragma unroll
            for (int ct = 0; ct < 4; ++ct)
                acc[rt][ct] = __builtin_amdgcn_mfma_f32_16x16x32_bf16(
                    af[rt], bf[ct], acc[rt][ct], 0, 0, 0);
        __syncthreads();
    }

    #pragma unroll
    for (int rt = 0; rt < 4; ++rt)
        #pragma unroll
        for (int ct = 0; ct < 4; ++ct)
            #pragma unroll
            for (int r = 0; r < 4; ++r) {
                const int row = bm + wr * 64 + rt * 16 + quad * 4 + r;
                const int col = bn + wc * 64 + ct * 16 + lrow;
                C[(size_t)row * ldc + col] = (OutT)acc[rt][ct][r];
            }
}

// ---------------------------------------------------------------------------
__global__ __launch_bounds__(256) void f32_to_bf16(
    const float* __restrict__ src, __bf16* __restrict__ dst)
{
    const size_t i = ((size_t)blockIdx.x * 256 + threadIdx.x) * 8;
    float4 a = *(const float4*)&src[i];
    float4 b = *(const float4*)&src[i + 4];
    bf16x8 o = {(__bf16)a.x, (__bf16)a.y, (__bf16)a.z, (__bf16)a.w,
                (__bf16)b.x, (__bf16)b.y, (__bf16)b.z, (__bf16)b.w};
    *(bf16x8*)&dst[i] = o;
}

// ---------------------------------------------------------------------------
// Weight convert + transpose: W[K,Nn] fp32 -> Wt[Nn,K] bf16. 64x64 LDS tiles.
// ---------------------------------------------------------------------------
__global__ __launch_bounds__(256) void wt_conv(
    const float* __restrict__ W, __bf16* __restrict__ Wt, int K, int Nn)
{
    __shared__ __bf16 t[64][72];
    const int kb = blockIdx.y * 64;
    const int nb = blockIdx.x * 64;
    {
        const int kl = threadIdx.x >> 2;
        const int c0 = (threadIdx.x & 3) * 16;
        const float* src = W + (size_t)(kb + kl) * Nn + nb + c0;
        #pragma unroll
        for (int u = 0; u < 4; ++u) {
            float4 f = *(const float4*)&src[u * 4];
            t[c0 + u * 4 + 0][kl] = (__bf16)f.x;
            t[c0 + u * 4 + 1][kl] = (__bf16)f.y;
            t[c0 + u * 4 + 2][kl] = (__bf16)f.z;
            t[c0 + u * 4 + 3][kl] = (__bf16)f.w;
        }
    }
    __syncthreads();
    {
        const int nl  = threadIdx.x >> 2;
        const int k0c = (threadIdx.x & 3) * 16;
        __bf16* dst = Wt + (size_t)(nb + nl) * K + kb + k0c;
        *(bf16x8*)&dst[0] = *(const bf16x8*)&t[nl][k0c];
        *(bf16x8*)&dst[8] = *(const bf16x8*)&t[nl][k0c + 8];
    }
}

// ---------------------------------------------------------------------------
// Fused RoPE + RMSNorm. Reads bf16 fused qkv [4096][3072] (q col 0, k col
// 1024), writes bf16 head-major (B,H,N,HD). One wave per row.
// ---------------------------------------------------------------------------
__global__ __launch_bounds__(256) void rope_rms_bf(
    const __bf16* __restrict__ qkv,
    const float* __restrict__ cs, const float* __restrict__ sn,
    __bf16* __restrict__ qbf, __bf16* __restrict__ kbf)
{
    const int row  = blockIdx.x * 4 + (threadIdx.x >> 6);  // (b*N + n)*H + h
    const int lane = threadIdx.x & 63;
    const int n    = (row >> 4) & (N_ - 1);
    const int b    = row >> 15;
    const int h    = row & 15;
    const int p    = lane >> 1;

    const float c = cs[n * (HD_ / 2) + p];
    const float s = sn[n * (HD_ / 2) + p];
    const size_t ibase = (size_t)(b * N_ + n) * 3072 + h * HD_ + lane;
    const size_t obase = ((size_t)(b * H_ + h) * N_ + n) * HD_ + lane;
    const bool odd = (lane & 1);

    {
        float val = (float)qkv[ibase];                  // q
        float partner = __shfl_xor(val, 1, 64);
        float r = odd ? fmaf(partner, s, val * c)
                      : (val * c - partner * s);
        float ss = r * r;
        #pragma unroll
        for (int off = 1; off < 64; off <<= 1) ss += __shfl_xor(ss, off, 64);
        qbf[obase] = (__bf16)(r * rsqrtf(ss * (1.0f / 64.0f) + EPS_));
    }
    {
        float val = (float)qkv[ibase + 1024];           // k
        float partner = __shfl_xor(val, 1, 64);
        float r = odd ? fmaf(partner, s, val * c)
                      : (val * c - partner * s);
        float ss = r * r;
        #pragma unroll
        for (int off = 1; off < 64; off <<= 1) ss += __shfl_xor(ss, off, 64);
        kbf[obase] = (__bf16)(r * rsqrtf(ss * (1.0f / 64.0f) + EPS_));
    }
}

// ---------------------------------------------------------------------------
// V transpose: bf16 v slice of qkv (cols 2048..3071) -> bf16 (B,H,HD,N).
// ---------------------------------------------------------------------------
__global__ __launch_bounds__(256) void vconv(
    const __bf16* __restrict__ qkv, __bf16* __restrict__ vt)
{
    __shared__ __bf16 tile[64][72];
    const int bh = blockIdx.y;
    const int b  = bh >> 4, h = bh & 15;
    const int n0 = blockIdx.x * 64;
    {
        const int nl = threadIdx.x >> 2;
        const int d0 = (threadIdx.x & 3) * 16;
        const __bf16* src = qkv + (size_t)(b * N_ + n0 + nl) * 3072 + 2048 + h * HD_ + d0;
        bf16x8 v0 = *(const bf16x8*)&src[0];
        bf16x8 v1 = *(const bf16x8*)&src[8];
        #pragma unroll
        for (int e = 0; e < 8; ++e) {
            tile[d0 + e][nl]     = v0[e];
            tile[d0 + 8 + e][nl] = v1[e];
        }
    }
    __syncthreads();
    {
        const int dl = threadIdx.x >> 2;
        const int nc = (threadIdx.x & 3) * 16;
        __bf16* dst = vt + ((size_t)(bh * HD_ + dl)) * N_ + n0 + nc;
        *(bf16x8*)&dst[0] = *(const bf16x8*)&tile[dl][nc];
        *(bf16x8*)&dst[8] = *(const bf16x8*)&tile[dl][nc + 8];
    }
}

// ---------------------------------------------------------------------------
// MFMA flash attention v4.1 (bf16 in, bf16 out).
// R7 = R6 with the causal-mask predicate FIXED:
//   a 32-key tile needs masking iff its max key (j0+31) can exceed the
//   wave's min row (i0):  masked <=> j0 + 31 > i0.
//   (R6 used j0+16 > i0, which let future keys through for waves w>=1.)
// Structure: K/V staged cooperatively into LDS via global_load_lds
// (m97-style 2-barrier loop); block = 64 q-rows of one bh (4 waves x 16);
// grid 32x32; dec trip count is block-uniform (all waves stage).
// ---------------------------------------------------------------------------
__global__ __launch_bounds__(256) void attn_mfma(
    const __bf16* __restrict__ qbf, const __bf16* __restrict__ kbf,
    const __bf16* __restrict__ vtbf, __bf16* __restrict__ o)
{
    __shared__ __bf16 Ks[32 * 64];       // [key][dim]
    __shared__ __bf16 Vs[64 * 32];       // [dim][key]
    __shared__ __bf16 Plds[4][16][36];   // [wave][qrow][key(padded)]

    const int tid  = threadIdx.x;
    const int w    = tid >> 6;
    const int lane = tid & 63;
    const int lrow = lane & 15;
    const int quad = lane >> 4;

    const int bh = blockIdx.x;                       // 0..31
    const int qb = gridDim.y - 1 - blockIdx.y;       // heavy-first
    const int b  = bh >> 4, h = bh & 15;
    const bool enc = (h < ENC_);
    const int i0 = qb * 64 + w * 16;                 // wave's 16 q-rows

    const __bf16* qbase = qbf  + (size_t)bh * N_ * HD_;
    const __bf16* kbase = kbf  + (size_t)bh * N_ * HD_;
    const __bf16* vbase = vtbf + (size_t)bh * HD_ * N_;

    // Staging: wave w stages K rows [w*8, w*8+8) (contiguous 1 KB) and
    // V dims [w*16, w*16+16) x 32 keys (per-lane scattered global, 1 KB LDS).
    const __bf16* kg = kbase + (size_t)(w * 8) * HD_ + lane * 8;
    const __bf16* vg = vbase + (size_t)(w * 16 + (lane >> 2)) * N_ + (lane & 3) * 8;
    __bf16* kl = &Ks[w * 512];
    __bf16* vl = &Vs[w * 512];

    bf16x8 qf[2];
    #pragma unroll
    for (int kc = 0; kc < 2; ++kc)
        qf[kc] = *(const bf16x8*)
            &qbase[(size_t)(i0 + lrow) * HD_ + kc * 32 + quad * 8];

    const f32x4 zero = {0.f, 0.f, 0.f, 0.f};
    f32x4 oacc[4];
    #pragma unroll
    for (int c = 0; c < 4; ++c) oacc[c] = zero;
    float lsum[4] = {};

    const float KS = 0.125f * 1.4426950408889634f;
    const float KO = -8.0f  * 1.4426950408889634f;

    // enc: all N keys; dec: keys [0, qb*64+64) (block-uniform trip count!)
    const int ntiles = enc ? (N_ >> 5) : (2 * qb + 2);
    const bool dec = !enc;

    for (int t = 0; t < ntiles; ++t) {
        const int j0 = t << 5;
        gld16(kg + (size_t)j0 * HD_, kl);
        gld16(vg + j0, vl);
        __syncthreads();   // drains vmcnt -> K/V tile visible in LDS

        bf16x8 kf0 = *(const bf16x8*)&Ks[lrow * 64 + quad * 8];
        bf16x8 kf1 = *(const bf16x8*)&Ks[lrow * 64 + 32 + quad * 8];
        bf16x8 kf2 = *(const bf16x8*)&Ks[(16 + lrow) * 64 + quad * 8];
        bf16x8 kf3 = *(const bf16x8*)&Ks[(16 + lrow) * 64 + 32 + quad * 8];

        f32x4 s0 = zero, s1 = zero;
        s0 = __builtin_amdgcn_mfma_f32_16x16x32_bf16(qf[0], kf0, s0, 0, 0, 0);
        s0 = __builtin_amdgcn_mfma_f32_16x16x32_bf16(qf[1], kf1, s0, 0, 0, 0);
        s1 = __builtin_amdgcn_mfma_f32_16x16x32_bf16(qf[0], kf2, s1, 0, 0, 0);
        s1 = __builtin_amdgcn_mfma_f32_16x16x32_bf16(qf[1], kf3, s1, 0, 0, 0);

        if (dec && (j0 + 31 > i0)) {   // FIXED: tile can reach above diagonal
            #pragma unroll
            for (int r = 0; r < 4; ++r) {
                const int i  = i0 + quad * 4 + r;
                float pA = (j0 + lrow      <= i) ? exp2f(fmaf(s0[r], KS, KO)) : 0.f;
                float pB = (j0 + 16 + lrow <= i) ? exp2f(fmaf(s1[r], KS, KO)) : 0.f;
                lsum[r] += pA + pB;
                Plds[w][quad * 4 + r][lrow]      = (__bf16)pA;
                Plds[w][quad * 4 + r][lrow + 16] = (__bf16)pB;
            }
        } else {
            #pragma unroll
            for (int r = 0; r < 4; ++r) {
                float pA = exp2f(fmaf(s0[r], KS, KO));
                float pB = exp2f(fmaf(s1[r], KS, KO));
                lsum[r] += pA + pB;
                Plds[w][quad * 4 + r][lrow]      = (__bf16)pA;
                Plds[w][quad * 4 + r][lrow + 16] = (__bf16)pB;
            }
        }

        bf16x8 vf0 = *(const bf16x8*)&Vs[(0 * 16 + lrow) * 32 + quad * 8];
        bf16x8 vf1 = *(const bf16x8*)&Vs[(1 * 16 + lrow) * 32 + quad * 8];
        bf16x8 vf2 = *(const bf16x8*)&Vs[(2 * 16 + lrow) * 32 + quad * 8];
        bf16x8 vf3 = *(const bf16x8*)&Vs[(3 * 16 + lrow) * 32 + quad * 8];

        bf16x8 pf = *(const bf16x8*)&Plds[w][lrow][quad * 8];
        oacc[0] = __builtin_amdgcn_mfma_f32_16x16x32_bf16(pf, vf0, oacc[0], 0, 0, 0);
        oacc[1] = __builtin_amdgcn_mfma_f32_16x16x32_bf16(pf, vf1, oacc[1], 0, 0, 0);
        oacc[2] = __builtin_amdgcn_mfma_f32_16x16x32_bf16(pf, vf2, oacc[2], 0, 0, 0);
        oacc[3] = __builtin_amdgcn_mfma_f32_16x16x32_bf16(pf, vf3, oacc[3], 0, 0, 0);

        __syncthreads();   // all waves done reading Ks/Vs before next stage
    }

    #pragma unroll
    for (int r = 0; r < 4; ++r) {
        float s = lsum[r];
        s += __shfl_xor(s, 1, 64);
        s += __shfl_xor(s, 2, 64);
        s += __shfl_xor(s, 4, 64);
        s += __shfl_xor(s, 8, 64);
        lsum[r] = 1.0f / s;
    }

    // O (bf16, [4096][1024], col = h*64 + dim); C-layout row=quad*4+r
    #pragma unroll
    for (int c = 0; c < 4; ++c)
        #pragma unroll
        for (int r = 0; r < 4; ++r) {
            const int i = i0 + quad * 4 + r;
            o[(size_t)(b * N_ + i) * D_ + h * HD_ + c * 16 + lrow] =
                (__bf16)(oacc[c][r] * lsum[r]);
        }
}

// ---------------------------------------------------------------------------
extern "C" void kernel_launch(void* const* d_in, const int* in_sizes, int n_in,
                              void* d_out, int out_size, void* d_ws, size_t ws_size,
                              hipStream_t stream)
{
    const float* x   = (const float*)d_in[0];
    const float* cs  = (const float*)d_in[1];
    const float* sn  = (const float*)d_in[2];
    const float* Wq  = (const float*)d_in[3];
    const float* Wk  = (const float*)d_in[4];
    const float* Wv  = (const float*)d_in[5];
    const float* Woe = (const float*)d_in[6];
    const float* Wod = (const float*)d_in[7];

    float* enc_out = (float*)d_out;
    float* dec_out = enc_out + (size_t)M_ * D_;

    // Workspace (57 MB), stream-ordered aliasing:
    //   [0,8)    xbf      -> reused as vtbf after QKV GEMM
    //   [8,14)   wqkv_t   (3072 x 1024 bf16)
    //   [14,16)  woe_t    (1024 x 1024 bf16)
    //   [16,17)  wod_t    (1024 x 512 bf16)
    //   [17,41)  qkv      (4096 x 3072 bf16) -> reused as obuf
    //   [41,49)  qbf head-major
    //   [49,57)  kbf head-major
    char* ws = (char*)d_ws;
    __bf16* xbf    = (__bf16*)(ws);
    __bf16* wqkv_t = (__bf16*)(ws + MB(8));
    __bf16* woe_t  = (__bf16*)(ws + MB(14));
    __bf16* wod_t  = (__bf16*)(ws + MB(16));
    __bf16* qkv    = (__bf16*)(ws + MB(17));
    __bf16* qbf    = (__bf16*)(ws + MB(41));
    __bf16* kbf    = (__bf16*)(ws + MB(49));
    __bf16* vtbf   = xbf;     // xbf dead after QKV GEMM
    __bf16* obuf   = qkv;     // qkv dead after rope_rms_bf + vconv

    f32_to_bf16<<<(M_ * D_) / (256 * 8), 256, 0, stream>>>(x, xbf);
    wt_conv<<<dim3(16, 16), 256, 0, stream>>>(Wq, wqkv_t,                   D_, D_);
    wt_conv<<<dim3(16, 16), 256, 0, stream>>>(Wk, wqkv_t + 1024 * 1024,     D_, D_);
    wt_conv<<<dim3(16, 16), 256, 0, stream>>>(Wv, wqkv_t + 2 * 1024 * 1024, D_, D_);
    wt_conv<<<dim3(16, 16), 256, 0, stream>>>(Woe, woe_t, D_, D_);
    wt_conv<<<dim3(16, 8),  256, 0, stream>>>(Wod, wod_t, 512, D_);

    gemm_bt<__bf16><<<dim3(3072 / 128, M_ / 128), 256, 0, stream>>>(
        xbf, wqkv_t, qkv, D_, D_, 0, 3072);

    rope_rms_bf<<<(B_ * N_ * H_) / 4, 256, 0, stream>>>(qkv, cs, sn, qbf, kbf);
    vconv<<<dim3(N_ / 64, B_ * H_), 256, 0, stream>>>(qkv, vtbf);

    // 32 bh x 32 q-blocks (reversed inside kernel: heavy first)
    attn_mfma<<<dim3(B_ * H_, N_ / 64), 256, 0, stream>>>(qbf, kbf, vtbf, obuf);

    gemm_bt<float><<<dim3(D_ / 128, M_ / 128), 256, 0, stream>>>(
        obuf, woe_t, enc_out, D_, D_, 0, D_);
    gemm_bt<float><<<dim3(D_ / 128, M_ / 128), 256, 0, stream>>>(
        obuf, wod_t, dec_out, 512, D_, 512, D_);
}

// Round 8
// 279.343 us; speedup vs baseline: 1.5509x; 1.0445x over previous
//
#include <hip/hip_runtime.h>
#include <hip/hip_bf16.h>
#include <math.h>

// Problem constants (fixed shapes from setup_inputs)
#define B_    2
#define N_    2048
#define D_    1024
#define H_    16
#define ENC_  8
#define HD_   64
#define EPS_  1e-5f
#define M_    (B_ * N_)        // 4096 rows for all GEMMs

typedef __bf16 bf16x8 __attribute__((ext_vector_type(8)));
typedef float  f32x4  __attribute__((ext_vector_type(4)));

#define MB(x) ((size_t)(x) * 1024 * 1024)

// Async global->LDS 16B copy. HW writes lds_base + lane*16 (wave-uniform LDS
// base); the GLOBAL address is per-lane, so scattered gathers are fine.
__device__ __forceinline__ void gld16(const __bf16* g, __bf16* l) {
    __builtin_amdgcn_global_load_lds(
        (const __attribute__((address_space(1))) void*)g,
        (__attribute__((address_space(3))) void*)l,
        16, 0, 0);
}

// ---------------------------------------------------------------------------
// bf16 MFMA GEMM, B pre-transposed: C[M,Nn] = A[M,K] @ Bt[Nn,K]^T.
// m97 structure: 128x128 tile, BK=32, 4 waves (2x2), each wave 4x4 MFMA
// 16x16x32 tiles, global_load_lds width-16 staging, 2-barrier K-loop.
// ---------------------------------------------------------------------------
template <typename OutT>
__global__ __launch_bounds__(256) void gemm_bt(
    const __bf16* __restrict__ A, const __bf16* __restrict__ Bt,
    OutT* __restrict__ C, int K, int lda, int aoff, int ldc)
{
    __shared__ __bf16 As[128 * 32];   // [row][k], 64 B rows
    __shared__ __bf16 Bs[128 * 32];   // [col][k]

    const int tid  = threadIdx.x;
    const int w    = tid >> 6;
    const int lane = tid & 63;
    const int lrow = lane & 15;
    const int quad = lane >> 4;
    const int wr   = w >> 1;           // wave row 0..1
    const int wc   = w & 1;            // wave col 0..1

    const int bm = blockIdx.y * 128;
    const int bn = blockIdx.x * 128;

    const int sr = lane >> 2;
    const int sc = (lane & 3) * 8;
    const __bf16* Ag0 = A  + (size_t)(bm +      w * 16 + sr) * lda + aoff + sc;
    const __bf16* Ag1 = A  + (size_t)(bm + 64 + w * 16 + sr) * lda + aoff + sc;
    const __bf16* Bg0 = Bt + (size_t)(bn +      w * 16 + sr) * K + sc;
    const __bf16* Bg1 = Bt + (size_t)(bn + 64 + w * 16 + sr) * K + sc;
    __bf16* Al0 = &As[w * 512];
    __bf16* Al1 = &As[2048 + w * 512];
    __bf16* Bl0 = &Bs[w * 512];
    __bf16* Bl1 = &Bs[2048 + w * 512];

    f32x4 acc[4][4];
    #pragma unroll
    for (int i = 0; i < 4; ++i)
        #pragma unroll
        for (int j = 0; j < 4; ++j) acc[i][j] = (f32x4){0.f, 0.f, 0.f, 0.f};

    for (int k0 = 0; k0 < K; k0 += 32) {
        gld16(Ag0 + k0, Al0);
        gld16(Ag1 + k0, Al1);
        gld16(Bg0 + k0, Bl0);
        gld16(Bg1 + k0, Bl1);
        __syncthreads();   // drains vmcnt -> LDS data visible

        bf16x8 af[4], bf[4];
        #pragma unroll
        for (int rt = 0; rt < 4; ++rt)
            af[rt] = *(const bf16x8*)&As[(wr * 64 + rt * 16 + lrow) * 32 + quad * 8];
        #pragma unroll
        for (int ct = 0; ct < 4; ++ct)
            bf[ct] = *(const bf16x8*)&Bs[(wc * 64 + ct * 16 + lrow) * 32 + quad * 8];

        #pragma unroll
        for (int rt = 0; rt < 4; ++rt)
            #pragma unroll
            for (int ct = 0; ct < 4; ++ct)
                acc[rt][ct] = __builtin_amdgcn_mfma_f32_16x16x32_bf16(
                    af[rt], bf[ct], acc[rt][ct], 0, 0, 0);
        __syncthreads();
    }

    #pragma unroll
    for (int rt = 0; rt < 4; ++rt)
        #pragma unroll
        for (int ct = 0; ct < 4; ++ct)
            #pragma unroll
            for (int r = 0; r < 4; ++r) {
                const int row = bm + wr * 64 + rt * 16 + quad * 4 + r;
                const int col = bn + wc * 64 + ct * 16 + lrow;
                C[(size_t)row * ldc + col] = (OutT)acc[rt][ct][r];
            }
}

// ---------------------------------------------------------------------------
__global__ __launch_bounds__(256) void f32_to_bf16(
    const float* __restrict__ src, __bf16* __restrict__ dst)
{
    const size_t i = ((size_t)blockIdx.x * 256 + threadIdx.x) * 8;
    float4 a = *(const float4*)&src[i];
    float4 b = *(const float4*)&src[i + 4];
    bf16x8 o = {(__bf16)a.x, (__bf16)a.y, (__bf16)a.z, (__bf16)a.w,
                (__bf16)b.x, (__bf16)b.y, (__bf16)b.z, (__bf16)b.w};
    *(bf16x8*)&dst[i] = o;
}

// ---------------------------------------------------------------------------
// Weight convert + transpose: W[K,Nn] fp32 -> Wt[Nn,K] bf16. 64x64 LDS tiles.
// ---------------------------------------------------------------------------
__global__ __launch_bounds__(256) void wt_conv(
    const float* __restrict__ W, __bf16* __restrict__ Wt, int K, int Nn)
{
    __shared__ __bf16 t[64][72];
    const int kb = blockIdx.y * 64;
    const int nb = blockIdx.x * 64;
    {
        const int kl = threadIdx.x >> 2;
        const int c0 = (threadIdx.x & 3) * 16;
        const float* src = W + (size_t)(kb + kl) * Nn + nb + c0;
        #pragma unroll
        for (int u = 0; u < 4; ++u) {
            float4 f = *(const float4*)&src[u * 4];
            t[c0 + u * 4 + 0][kl] = (__bf16)f.x;
            t[c0 + u * 4 + 1][kl] = (__bf16)f.y;
            t[c0 + u * 4 + 2][kl] = (__bf16)f.z;
            t[c0 + u * 4 + 3][kl] = (__bf16)f.w;
        }
    }
    __syncthreads();
    {
        const int nl  = threadIdx.x >> 2;
        const int k0c = (threadIdx.x & 3) * 16;
        __bf16* dst = Wt + (size_t)(nb + nl) * K + kb + k0c;
        *(bf16x8*)&dst[0] = *(const bf16x8*)&t[nl][k0c];
        *(bf16x8*)&dst[8] = *(const bf16x8*)&t[nl][k0c + 8];
    }
}

// ---------------------------------------------------------------------------
// Fused RoPE + RMSNorm. Reads bf16 fused qkv [4096][3072] (q col 0, k col
// 1024), writes bf16 head-major (B,H,N,HD). One wave per row.
// ---------------------------------------------------------------------------
__global__ __launch_bounds__(256) void rope_rms_bf(
    const __bf16* __restrict__ qkv,
    const float* __restrict__ cs, const float* __restrict__ sn,
    __bf16* __restrict__ qbf, __bf16* __restrict__ kbf)
{
    const int row  = blockIdx.x * 4 + (threadIdx.x >> 6);  // (b*N + n)*H + h
    const int lane = threadIdx.x & 63;
    const int n    = (row >> 4) & (N_ - 1);
    const int b    = row >> 15;
    const int h    = row & 15;
    const int p    = lane >> 1;

    const float c = cs[n * (HD_ / 2) + p];
    const float s = sn[n * (HD_ / 2) + p];
    const size_t ibase = (size_t)(b * N_ + n) * 3072 + h * HD_ + lane;
    const size_t obase = ((size_t)(b * H_ + h) * N_ + n) * HD_ + lane;
    const bool odd = (lane & 1);

    {
        float val = (float)qkv[ibase];                  // q
        float partner = __shfl_xor(val, 1, 64);
        float r = odd ? fmaf(partner, s, val * c)
                      : (val * c - partner * s);
        float ss = r * r;
        #pragma unroll
        for (int off = 1; off < 64; off <<= 1) ss += __shfl_xor(ss, off, 64);
        qbf[obase] = (__bf16)(r * rsqrtf(ss * (1.0f / 64.0f) + EPS_));
    }
    {
        float val = (float)qkv[ibase + 1024];           // k
        float partner = __shfl_xor(val, 1, 64);
        float r = odd ? fmaf(partner, s, val * c)
                      : (val * c - partner * s);
        float ss = r * r;
        #pragma unroll
        for (int off = 1; off < 64; off <<= 1) ss += __shfl_xor(ss, off, 64);
        kbf[obase] = (__bf16)(r * rsqrtf(ss * (1.0f / 64.0f) + EPS_));
    }
}

// ---------------------------------------------------------------------------
// V transpose: bf16 v slice of qkv (cols 2048..3071) -> bf16 (B,H,HD,N).
// ---------------------------------------------------------------------------
__global__ __launch_bounds__(256) void vconv(
    const __bf16* __restrict__ qkv, __bf16* __restrict__ vt)
{
    __shared__ __bf16 tile[64][72];
    const int bh = blockIdx.y;
    const int b  = bh >> 4, h = bh & 15;
    const int n0 = blockIdx.x * 64;
    {
        const int nl = threadIdx.x >> 2;
        const int d0 = (threadIdx.x & 3) * 16;
        const __bf16* src = qkv + (size_t)(b * N_ + n0 + nl) * 3072 + 2048 + h * HD_ + d0;
        bf16x8 v0 = *(const bf16x8*)&src[0];
        bf16x8 v1 = *(const bf16x8*)&src[8];
        #pragma unroll
        for (int e = 0; e < 8; ++e) {
            tile[d0 + e][nl]     = v0[e];
            tile[d0 + 8 + e][nl] = v1[e];
        }
    }
    __syncthreads();
    {
        const int dl = threadIdx.x >> 2;
        const int nc = (threadIdx.x & 3) * 16;
        __bf16* dst = vt + ((size_t)(bh * HD_ + dl)) * N_ + n0 + nc;
        *(bf16x8*)&dst[0] = *(const bf16x8*)&tile[dl][nc];
        *(bf16x8*)&dst[8] = *(const bf16x8*)&tile[dl][nc + 8];
    }
}

// ---------------------------------------------------------------------------
// MFMA flash attention v5 (bf16 in, bf16 out).
// R8 changes vs R7 (structure otherwise identical):
//  1. Chunk-transposed K/V LDS layouts (conflict-free reads; padding is
//     impossible under global_load_lds's contiguous-write rule):
//       K: 16B chunk p = dimchunk*32 + key   (8 dimchunks x 32 keys)
//       V: 16B chunk p = keychunk*64 + dim   (4 keychunks x 64 dims)
//     Read word residue = 4*(lrow mod 8) -> 2 lanes/bank (free, m136).
//     R7's Ks rows were 32 words (= 0 mod 32): 16-way conflicts, 1.27e7.
//     Staging lane mapping re-derived so wave w's lane l writes chunk
//     64w + l (lane-contiguous LDS, as the HW requires).
//  2. Double-buffered LDS + ONE barrier per tile: stage tile t+1 right
//     after the barrier, compute tile t from the other buffer. The
//     vmcnt(0)-before-barrier drain for t+1 then lands after a full
//     tile of compute -> staging latency hidden (R7 exposed it twice).
// ---------------------------------------------------------------------------
__global__ __launch_bounds__(256) void attn_mfma(
    const __bf16* __restrict__ qbf, const __bf16* __restrict__ kbf,
    const __bf16* __restrict__ vtbf, __bf16* __restrict__ o)
{
    __shared__ __bf16 Ks[2][32 * 64];    // chunk-transposed, 4 KB each
    __shared__ __bf16 Vs[2][64 * 32];
    __shared__ __bf16 Plds[4][16][36];   // [wave][qrow][key(padded)]

    const int tid  = threadIdx.x;
    const int w    = tid >> 6;
    const int lane = tid & 63;
    const int lrow = lane & 15;
    const int quad = lane >> 4;

    const int bh = blockIdx.x;                       // 0..31
    const int qb = gridDim.y - 1 - blockIdx.y;       // heavy-first
    const int b  = bh >> 4, h = bh & 15;
    const bool enc = (h < ENC_);
    const int i0 = qb * 64 + w * 16;                 // wave's 16 q-rows

    const __bf16* qbase = qbf  + (size_t)bh * N_ * HD_;
    const __bf16* kbase = kbf  + (size_t)bh * N_ * HD_;
    const __bf16* vbase = vtbf + (size_t)bh * HD_ * N_;

    // Staging pointers (chunk 64w + lane):
    //   K: key = lane&31, dimchunk = 2w + (lane>>5)
    //   V: dim = lane,    keychunk = w
    const __bf16* kg = kbase + (size_t)(lane & 31) * HD_ + (2 * w + (lane >> 5)) * 8;
    const __bf16* vg = vbase + (size_t)lane * N_ + w * 8;

    bf16x8 qf[2];
    #pragma unroll
    for (int kc = 0; kc < 2; ++kc)
        qf[kc] = *(const bf16x8*)
            &qbase[(size_t)(i0 + lrow) * HD_ + kc * 32 + quad * 8];

    const f32x4 zero = {0.f, 0.f, 0.f, 0.f};
    f32x4 oacc[4];
    #pragma unroll
    for (int c = 0; c < 4; ++c) oacc[c] = zero;
    float lsum[4] = {};

    const float KSc = 0.125f * 1.4426950408889634f;
    const float KOc = -8.0f  * 1.4426950408889634f;

    // enc: all N keys; dec: keys [0, qb*64+64) (block-uniform trip count)
    const int ntiles = enc ? (N_ >> 5) : (2 * qb + 2);
    const bool dec = !enc;

    // stage tile (j0 = t*32) into buffer bb
    auto stage = [&](int t, int bb) {
        const int j0 = t << 5;
        gld16(kg + (size_t)j0 * HD_, &Ks[bb][w * 512]);
        gld16(vg + j0, &Vs[bb][w * 512]);
    };

    stage(0, 0);
    for (int t = 0; t < ntiles; ++t) {
        const int bb = t & 1;
        const int j0 = t << 5;
        __syncthreads();            // buf bb staged; prev compute done
        if (t + 1 < ntiles) stage(t + 1, bb ^ 1);

        // K fragments: chunk p = dimchunk*32 + key
        bf16x8 kf0 = *(const bf16x8*)&Ks[bb][(quad * 32 + lrow) * 8];
        bf16x8 kf1 = *(const bf16x8*)&Ks[bb][((4 + quad) * 32 + lrow) * 8];
        bf16x8 kf2 = *(const bf16x8*)&Ks[bb][(quad * 32 + 16 + lrow) * 8];
        bf16x8 kf3 = *(const bf16x8*)&Ks[bb][((4 + quad) * 32 + 16 + lrow) * 8];

        f32x4 s0 = zero, s1 = zero;
        s0 = __builtin_amdgcn_mfma_f32_16x16x32_bf16(qf[0], kf0, s0, 0, 0, 0);
        s0 = __builtin_amdgcn_mfma_f32_16x16x32_bf16(qf[1], kf1, s0, 0, 0, 0);
        s1 = __builtin_amdgcn_mfma_f32_16x16x32_bf16(qf[0], kf2, s1, 0, 0, 0);
        s1 = __builtin_amdgcn_mfma_f32_16x16x32_bf16(qf[1], kf3, s1, 0, 0, 0);

        if (dec && (j0 + 31 > i0)) {   // tile can reach above the diagonal
            #pragma unroll
            for (int r = 0; r < 4; ++r) {
                const int i  = i0 + quad * 4 + r;
                float pA = (j0 + lrow      <= i) ? exp2f(fmaf(s0[r], KSc, KOc)) : 0.f;
                float pB = (j0 + 16 + lrow <= i) ? exp2f(fmaf(s1[r], KSc, KOc)) : 0.f;
                lsum[r] += pA + pB;
                Plds[w][quad * 4 + r][lrow]      = (__bf16)pA;
                Plds[w][quad * 4 + r][lrow + 16] = (__bf16)pB;
            }
        } else {
            #pragma unroll
            for (int r = 0; r < 4; ++r) {
                float pA = exp2f(fmaf(s0[r], KSc, KOc));
                float pB = exp2f(fmaf(s1[r], KSc, KOc));
                lsum[r] += pA + pB;
                Plds[w][quad * 4 + r][lrow]      = (__bf16)pA;
                Plds[w][quad * 4 + r][lrow + 16] = (__bf16)pB;
            }
        }

        // V fragments: chunk p = keychunk*64 + dim
        bf16x8 vf0 = *(const bf16x8*)&Vs[bb][(quad * 64 +  0 + lrow) * 8];
        bf16x8 vf1 = *(const bf16x8*)&Vs[bb][(quad * 64 + 16 + lrow) * 8];
        bf16x8 vf2 = *(const bf16x8*)&Vs[bb][(quad * 64 + 32 + lrow) * 8];
        bf16x8 vf3 = *(const bf16x8*)&Vs[bb][(quad * 64 + 48 + lrow) * 8];

        bf16x8 pf = *(const bf16x8*)&Plds[w][lrow][quad * 8];
        oacc[0] = __builtin_amdgcn_mfma_f32_16x16x32_bf16(pf, vf0, oacc[0], 0, 0, 0);
        oacc[1] = __builtin_amdgcn_mfma_f32_16x16x32_bf16(pf, vf1, oacc[1], 0, 0, 0);
        oacc[2] = __builtin_amdgcn_mfma_f32_16x16x32_bf16(pf, vf2, oacc[2], 0, 0, 0);
        oacc[3] = __builtin_amdgcn_mfma_f32_16x16x32_bf16(pf, vf3, oacc[3], 0, 0, 0);
    }

    #pragma unroll
    for (int r = 0; r < 4; ++r) {
        float s = lsum[r];
        s += __shfl_xor(s, 1, 64);
        s += __shfl_xor(s, 2, 64);
        s += __shfl_xor(s, 4, 64);
        s += __shfl_xor(s, 8, 64);
        lsum[r] = 1.0f / s;
    }

    // O (bf16, [4096][1024], col = h*64 + dim); C-layout row=quad*4+r
    #pragma unroll
    for (int c = 0; c < 4; ++c)
        #pragma unroll
        for (int r = 0; r < 4; ++r) {
            const int i = i0 + quad * 4 + r;
            o[(size_t)(b * N_ + i) * D_ + h * HD_ + c * 16 + lrow] =
                (__bf16)(oacc[c][r] * lsum[r]);
        }
}

// ---------------------------------------------------------------------------
extern "C" void kernel_launch(void* const* d_in, const int* in_sizes, int n_in,
                              void* d_out, int out_size, void* d_ws, size_t ws_size,
                              hipStream_t stream)
{
    const float* x   = (const float*)d_in[0];
    const float* cs  = (const float*)d_in[1];
    const float* sn  = (const float*)d_in[2];
    const float* Wq  = (const float*)d_in[3];
    const float* Wk  = (const float*)d_in[4];
    const float* Wv  = (const float*)d_in[5];
    const float* Woe = (const float*)d_in[6];
    const float* Wod = (const float*)d_in[7];

    float* enc_out = (float*)d_out;
    float* dec_out = enc_out + (size_t)M_ * D_;

    // Workspace (57 MB), stream-ordered aliasing:
    //   [0,8)    xbf      -> reused as vtbf after QKV GEMM
    //   [8,14)   wqkv_t   (3072 x 1024 bf16)
    //   [14,16)  woe_t    (1024 x 1024 bf16)
    //   [16,17)  wod_t    (1024 x 512 bf16)
    //   [17,41)  qkv      (4096 x 3072 bf16) -> reused as obuf
    //   [41,49)  qbf head-major
    //   [49,57)  kbf head-major
    char* ws = (char*)d_ws;
    __bf16* xbf    = (__bf16*)(ws);
    __bf16* wqkv_t = (__bf16*)(ws + MB(8));
    __bf16* woe_t  = (__bf16*)(ws + MB(14));
    __bf16* wod_t  = (__bf16*)(ws + MB(16));
    __bf16* qkv    = (__bf16*)(ws + MB(17));
    __bf16* qbf    = (__bf16*)(ws + MB(41));
    __bf16* kbf    = (__bf16*)(ws + MB(49));
    __bf16* vtbf   = xbf;     // xbf dead after QKV GEMM
    __bf16* obuf   = qkv;     // qkv dead after rope_rms_bf + vconv

    f32_to_bf16<<<(M_ * D_) / (256 * 8), 256, 0, stream>>>(x, xbf);
    wt_conv<<<dim3(16, 16), 256, 0, stream>>>(Wq, wqkv_t,                   D_, D_);
    wt_conv<<<dim3(16, 16), 256, 0, stream>>>(Wk, wqkv_t + 1024 * 1024,     D_, D_);
    wt_conv<<<dim3(16, 16), 256, 0, stream>>>(Wv, wqkv_t + 2 * 1024 * 1024, D_, D_);
    wt_conv<<<dim3(16, 16), 256, 0, stream>>>(Woe, woe_t, D_, D_);
    wt_conv<<<dim3(16, 8),  256, 0, stream>>>(Wod, wod_t, 512, D_);

    gemm_bt<__bf16><<<dim3(3072 / 128, M_ / 128), 256, 0, stream>>>(
        xbf, wqkv_t, qkv, D_, D_, 0, 3072);

    rope_rms_bf<<<(B_ * N_ * H_) / 4, 256, 0, stream>>>(qkv, cs, sn, qbf, kbf);
    vconv<<<dim3(N_ / 64, B_ * H_), 256, 0, stream>>>(qkv, vtbf);

    // 32 bh x 32 q-blocks (reversed inside kernel: heavy first)
    attn_mfma<<<dim3(B_ * H_, N_ / 64), 256, 0, stream>>>(qbf, kbf, vtbf, obuf);

    gemm_bt<float><<<dim3(D_ / 128, M_ / 128), 256, 0, stream>>>(
        obuf, woe_t, enc_out, D_, D_, 0, D_);
    gemm_bt<float><<<dim3(D_ / 128, M_ / 128), 256, 0, stream>>>(
        obuf, wod_t, dec_out, 512, D_, 512, D_);
}

// Round 9
// 250.892 us; speedup vs baseline: 1.7268x; 1.1134x over previous
//
#include <hip/hip_runtime.h>
#include <hip/hip_bf16.h>
#include <math.h>

// Problem constants (fixed shapes from setup_inputs)
#define B_    2
#define N_    2048
#define D_    1024
#define H_    16
#define ENC_  8
#define HD_   64
#define EPS_  1e-5f
#define M_    (B_ * N_)        // 4096 rows for all GEMMs

typedef __bf16 bf16x8 __attribute__((ext_vector_type(8)));
typedef float  f32x4  __attribute__((ext_vector_type(4)));

#define MB(x) ((size_t)(x) * 1024 * 1024)

// Async global->LDS 16B copy. HW writes lds_base + lane*16 (wave-uniform LDS
// base); the GLOBAL address is per-lane, so scattered gathers are fine.
__device__ __forceinline__ void gld16(const __bf16* g, __bf16* l) {
    __builtin_amdgcn_global_load_lds(
        (const __attribute__((address_space(1))) void*)g,
        (__attribute__((address_space(3))) void*)l,
        16, 0, 0);
}

// ---------------------------------------------------------------------------
// Shared MFMA GEMM core (m97 structure): C[128x128 tile] = A @ Bt^T.
// 4 waves (2x2), each wave 4x4 16x16x32 MFMAs, global_load_lds staging.
// ---------------------------------------------------------------------------
template <typename OutT>
__device__ __forceinline__ void gemm_core(
    const __bf16* __restrict__ A, const __bf16* __restrict__ Bt,
    OutT* __restrict__ C, int K, int lda, int aoff, int ldc,
    int bm, int bn, __bf16* As, __bf16* Bs)
{
    const int tid  = threadIdx.x;
    const int w    = tid >> 6;
    const int lane = tid & 63;
    const int lrow = lane & 15;
    const int quad = lane >> 4;
    const int wr   = w >> 1;
    const int wc   = w & 1;

    const int sr = lane >> 2;
    const int sc = (lane & 3) * 8;
    const __bf16* Ag0 = A  + (size_t)(bm +      w * 16 + sr) * lda + aoff + sc;
    const __bf16* Ag1 = A  + (size_t)(bm + 64 + w * 16 + sr) * lda + aoff + sc;
    const __bf16* Bg0 = Bt + (size_t)(bn +      w * 16 + sr) * K + sc;
    const __bf16* Bg1 = Bt + (size_t)(bn + 64 + w * 16 + sr) * K + sc;
    __bf16* Al0 = &As[w * 512];
    __bf16* Al1 = &As[2048 + w * 512];
    __bf16* Bl0 = &Bs[w * 512];
    __bf16* Bl1 = &Bs[2048 + w * 512];

    f32x4 acc[4][4];
    #pragma unroll
    for (int i = 0; i < 4; ++i)
        #pragma unroll
        for (int j = 0; j < 4; ++j) acc[i][j] = (f32x4){0.f, 0.f, 0.f, 0.f};

    for (int k0 = 0; k0 < K; k0 += 32) {
        gld16(Ag0 + k0, Al0);
        gld16(Ag1 + k0, Al1);
        gld16(Bg0 + k0, Bl0);
        gld16(Bg1 + k0, Bl1);
        __syncthreads();

        bf16x8 af[4], bf[4];
        #pragma unroll
        for (int rt = 0; rt < 4; ++rt)
            af[rt] = *(const bf16x8*)&As[(wr * 64 + rt * 16 + lrow) * 32 + quad * 8];
        #pragma unroll
        for (int ct = 0; ct < 4; ++ct)
            bf[ct] = *(const bf16x8*)&Bs[(wc * 64 + ct * 16 + lrow) * 32 + quad * 8];

        #pragma unroll
        for (int rt = 0; rt < 4; ++rt)
            #pragma unroll
            for (int ct = 0; ct < 4; ++ct)
                acc[rt][ct] = __builtin_amdgcn_mfma_f32_16x16x32_bf16(
                    af[rt], bf[ct], acc[rt][ct], 0, 0, 0);
        __syncthreads();
    }

    #pragma unroll
    for (int rt = 0; rt < 4; ++rt)
        #pragma unroll
        for (int ct = 0; ct < 4; ++ct)
            #pragma unroll
            for (int r = 0; r < 4; ++r) {
                const int row = bm + wr * 64 + rt * 16 + quad * 4 + r;
                const int col = bn + wc * 64 + ct * 16 + lrow;
                C[(size_t)row * ldc + col] = (OutT)acc[rt][ct][r];
            }
}

// QKV projection GEMM (bf16 out)
__global__ __launch_bounds__(256) void gemm_qkv(
    const __bf16* __restrict__ A, const __bf16* __restrict__ Bt,
    __bf16* __restrict__ C)
{
    __shared__ __bf16 As[128 * 32];
    __shared__ __bf16 Bs[128 * 32];
    gemm_core<__bf16>(A, Bt, C, D_, D_, 0, 3072,
                      blockIdx.y * 128, blockIdx.x * 128, As, Bs);
}

// Merged output projections: bx<8 -> enc (K=1024), bx>=8 -> dec (K=512).
__global__ __launch_bounds__(256) void gemm_out(
    const __bf16* __restrict__ A, const __bf16* __restrict__ Woe,
    const __bf16* __restrict__ Wod, float* __restrict__ Cenc,
    float* __restrict__ Cdec)
{
    __shared__ __bf16 As[128 * 32];
    __shared__ __bf16 Bs[128 * 32];
    const int bx = blockIdx.x;
    if (bx < 8) {
        gemm_core<float>(A, Woe, Cenc, 1024, D_, 0, D_,
                         blockIdx.y * 128, bx * 128, As, Bs);
    } else {
        gemm_core<float>(A, Wod, Cdec, 512, D_, 512, D_,
                         blockIdx.y * 128, (bx - 8) * 128, As, Bs);
    }
}

// ---------------------------------------------------------------------------
__global__ __launch_bounds__(256) void f32_to_bf16(
    const float* __restrict__ src, __bf16* __restrict__ dst)
{
    const size_t i = ((size_t)blockIdx.x * 256 + threadIdx.x) * 8;
    float4 a = *(const float4*)&src[i];
    float4 b = *(const float4*)&src[i + 4];
    bf16x8 o = {(__bf16)a.x, (__bf16)a.y, (__bf16)a.z, (__bf16)a.w,
                (__bf16)b.x, (__bf16)b.y, (__bf16)b.z, (__bf16)b.w};
    *(bf16x8*)&dst[i] = o;
}

// ---------------------------------------------------------------------------
// All 5 weight converts (fp32 W[K][Nn] -> bf16 Wt[Nn][K]) in one launch.
// grid (16, 16, 5); z=4 (Wod, K=512) uses only y<8.
// ---------------------------------------------------------------------------
struct WtArgs {
    const float* W[5];
    __bf16*      Wt[5];
    int          K[5];      // rows of W == inner stride of Wt
    int          nyb[5];    // grid-y blocks used
};

__global__ __launch_bounds__(256) void wt_conv_all(WtArgs a)
{
    const int z = blockIdx.z;
    if (blockIdx.y >= a.nyb[z]) return;
    const float* W  = a.W[z];
    __bf16*      Wt = a.Wt[z];
    const int    K  = a.K[z];

    __shared__ __bf16 t[64][72];
    const int kb = blockIdx.y * 64;
    const int nb = blockIdx.x * 64;
    {
        const int kl = threadIdx.x >> 2;
        const int c0 = (threadIdx.x & 3) * 16;
        const float* src = W + (size_t)(kb + kl) * D_ + nb + c0;
        #pragma unroll
        for (int u = 0; u < 4; ++u) {
            float4 f = *(const float4*)&src[u * 4];
            t[c0 + u * 4 + 0][kl] = (__bf16)f.x;
            t[c0 + u * 4 + 1][kl] = (__bf16)f.y;
            t[c0 + u * 4 + 2][kl] = (__bf16)f.z;
            t[c0 + u * 4 + 3][kl] = (__bf16)f.w;
        }
    }
    __syncthreads();
    {
        const int nl  = threadIdx.x >> 2;
        const int k0c = (threadIdx.x & 3) * 16;
        __bf16* dst = Wt + (size_t)(nb + nl) * K + kb + k0c;
        *(bf16x8*)&dst[0] = *(const bf16x8*)&t[nl][k0c];
        *(bf16x8*)&dst[8] = *(const bf16x8*)&t[nl][k0c + 8];
    }
}

// ---------------------------------------------------------------------------
// Fused RoPE+RMSNorm (q,k) + V transpose, one launch.
// blocks [0,16384): rope path (4 rows/block); [16384,17408): vconv path.
// ---------------------------------------------------------------------------
__global__ __launch_bounds__(256) void rope_vconv(
    const __bf16* __restrict__ qkv,
    const float* __restrict__ cs, const float* __restrict__ sn,
    __bf16* __restrict__ qbf, __bf16* __restrict__ kbf,
    __bf16* __restrict__ vt)
{
    if (blockIdx.x < 16384) {
        const int row  = blockIdx.x * 4 + (threadIdx.x >> 6);  // (b*N+n)*H + h
        const int lane = threadIdx.x & 63;
        const int n    = (row >> 4) & (N_ - 1);
        const int b    = row >> 15;
        const int h    = row & 15;
        const int p    = lane >> 1;

        const float c = cs[n * (HD_ / 2) + p];
        const float s = sn[n * (HD_ / 2) + p];
        const size_t ibase = (size_t)(b * N_ + n) * 3072 + h * HD_ + lane;
        const size_t obase = ((size_t)(b * H_ + h) * N_ + n) * HD_ + lane;
        const bool odd = (lane & 1);

        {
            float val = (float)qkv[ibase];                  // q
            float partner = __shfl_xor(val, 1, 64);
            float r = odd ? fmaf(partner, s, val * c)
                          : (val * c - partner * s);
            float ss = r * r;
            #pragma unroll
            for (int off = 1; off < 64; off <<= 1) ss += __shfl_xor(ss, off, 64);
            qbf[obase] = (__bf16)(r * rsqrtf(ss * (1.0f / 64.0f) + EPS_));
        }
        {
            float val = (float)qkv[ibase + 1024];           // k
            float partner = __shfl_xor(val, 1, 64);
            float r = odd ? fmaf(partner, s, val * c)
                          : (val * c - partner * s);
            float ss = r * r;
            #pragma unroll
            for (int off = 1; off < 64; off <<= 1) ss += __shfl_xor(ss, off, 64);
            kbf[obase] = (__bf16)(r * rsqrtf(ss * (1.0f / 64.0f) + EPS_));
        }
    } else {
        __shared__ __bf16 tile[64][72];
        const int bx = blockIdx.x - 16384;
        const int bh = bx >> 5;
        const int b  = bh >> 4, h = bh & 15;
        const int n0 = (bx & 31) * 64;
        {
            const int nl = threadIdx.x >> 2;
            const int d0 = (threadIdx.x & 3) * 16;
            const __bf16* src =
                qkv + (size_t)(b * N_ + n0 + nl) * 3072 + 2048 + h * HD_ + d0;
            bf16x8 v0 = *(const bf16x8*)&src[0];
            bf16x8 v1 = *(const bf16x8*)&src[8];
            #pragma unroll
            for (int e = 0; e < 8; ++e) {
                tile[d0 + e][nl]     = v0[e];
                tile[d0 + 8 + e][nl] = v1[e];
            }
        }
        __syncthreads();
        {
            const int dl = threadIdx.x >> 2;
            const int nc = (threadIdx.x & 3) * 16;
            __bf16* dst = vt + ((size_t)(bh * HD_ + dl)) * N_ + n0 + nc;
            *(bf16x8*)&dst[0] = *(const bf16x8*)&tile[dl][nc];
            *(bf16x8*)&dst[8] = *(const bf16x8*)&tile[dl][nc + 8];
        }
    }
}

// ---------------------------------------------------------------------------
// MFMA flash attention v6 (bf16 in, bf16 out).
// R9 change vs R8: 64-key staging tiles (double-buffered, one barrier per
// 64 keys -> half the barrier/drain count). Each stage = 16 KB (K 8 KB +
// V 8 KB, 4 gld16/wave); compute = two 32-key passes using R8's verified
// fragment/P-layout code.
//   K LDS: chunk p = dimchunk*64 + key   (8 dc x 64 keys)
//   V LDS: chunk p = keyoct*64 + dim     (8 ko x 64 dims)
// Block = 64 q-rows of one bh (4 waves x 16); grid 32 x 32, heavy-first.
// ---------------------------------------------------------------------------
__global__ __launch_bounds__(256) void attn_mfma(
    const __bf16* __restrict__ qbf, const __bf16* __restrict__ kbf,
    const __bf16* __restrict__ vtbf, __bf16* __restrict__ o)
{
    __shared__ __bf16 Ks[2][4096];       // 8 KB per buffer
    __shared__ __bf16 Vs[2][4096];
    __shared__ __bf16 Plds[4][16][36];   // [wave][qrow][key(padded)]

    const int tid  = threadIdx.x;
    const int w    = tid >> 6;
    const int lane = tid & 63;
    const int lrow = lane & 15;
    const int quad = lane >> 4;

    const int bh = blockIdx.x;                       // 0..31
    const int qb = gridDim.y - 1 - blockIdx.y;       // heavy-first
    const int b  = bh >> 4, h = bh & 15;
    const bool enc = (h < ENC_);
    const int i0 = qb * 64 + w * 16;                 // wave's 16 q-rows

    const __bf16* qbase = qbf  + (size_t)bh * N_ * HD_;
    const __bf16* kbase = kbf  + (size_t)bh * N_ * HD_;
    const __bf16* vbase = vtbf + (size_t)bh * HD_ * N_;

    // Staging (wave w handles chunk groups m = w and m = w+4):
    //   K group m: lane l -> key l, dims [m*8, m*8+8)
    //   V group m: lane l -> dim l, keys [m*8, m*8+8)
    const __bf16* kg0 = kbase + (size_t)lane * HD_ + w * 8;        // m=w
    const __bf16* kg1 = kbase + (size_t)lane * HD_ + (w + 4) * 8;  // m=w+4
    const __bf16* vg  = vbase + (size_t)lane * N_;

    bf16x8 qf[2];
    #pragma unroll
    for (int kc = 0; kc < 2; ++kc)
        qf[kc] = *(const bf16x8*)
            &qbase[(size_t)(i0 + lrow) * HD_ + kc * 32 + quad * 8];

    const f32x4 zero = {0.f, 0.f, 0.f, 0.f};
    f32x4 oacc[4];
    #pragma unroll
    for (int c = 0; c < 4; ++c) oacc[c] = zero;
    float lsum[4] = {};

    const float KSc = 0.125f * 1.4426950408889634f;
    const float KOc = -8.0f  * 1.4426950408889634f;

    // 64-key tiles. enc: all N; dec: keys [0, qb*64+64).
    const int ntiles = enc ? (N_ >> 6) : (qb + 1);
    const bool dec = !enc;

    auto stage = [&](int t, int bb) {
        const int j0 = t << 6;
        gld16(kg0 + (size_t)j0 * HD_, &Ks[bb][(w)     * 512]);
        gld16(kg1 + (size_t)j0 * HD_, &Ks[bb][(w + 4) * 512]);
        gld16(vg + j0 + w * 8,        &Vs[bb][(w)     * 512]);
        gld16(vg + j0 + (w + 4) * 8,  &Vs[bb][(w + 4) * 512]);
    };

    stage(0, 0);
    for (int t = 0; t < ntiles; ++t) {
        const int bb = t & 1;
        __syncthreads();            // buf bb staged; prev compute done
        if (t + 1 < ntiles) stage(t + 1, bb ^ 1);

        #pragma unroll
        for (int s = 0; s < 2; ++s) {
            const int jp = (t << 6) + s * 32;   // pass keys [jp, jp+32)

            // K fragments: elem ((kc*4+quad)*64 + s*32 + u*16 + lrow)*8
            bf16x8 kf0 = *(const bf16x8*)&Ks[bb][((quad)     * 64 + s * 32 + lrow) * 8];
            bf16x8 kf1 = *(const bf16x8*)&Ks[bb][((4 + quad) * 64 + s * 32 + lrow) * 8];
            bf16x8 kf2 = *(const bf16x8*)&Ks[bb][((quad)     * 64 + s * 32 + 16 + lrow) * 8];
            bf16x8 kf3 = *(const bf16x8*)&Ks[bb][((4 + quad) * 64 + s * 32 + 16 + lrow) * 8];

            f32x4 s0 = zero, s1 = zero;
            s0 = __builtin_amdgcn_mfma_f32_16x16x32_bf16(qf[0], kf0, s0, 0, 0, 0);
            s0 = __builtin_amdgcn_mfma_f32_16x16x32_bf16(qf[1], kf1, s0, 0, 0, 0);
            s1 = __builtin_amdgcn_mfma_f32_16x16x32_bf16(qf[0], kf2, s1, 0, 0, 0);
            s1 = __builtin_amdgcn_mfma_f32_16x16x32_bf16(qf[1], kf3, s1, 0, 0, 0);

            if (dec && (jp + 31 > i0)) {   // pass can reach above diagonal
                #pragma unroll
                for (int r = 0; r < 4; ++r) {
                    const int i  = i0 + quad * 4 + r;
                    float pA = (jp + lrow      <= i) ? exp2f(fmaf(s0[r], KSc, KOc)) : 0.f;
                    float pB = (jp + 16 + lrow <= i) ? exp2f(fmaf(s1[r], KSc, KOc)) : 0.f;
                    lsum[r] += pA + pB;
                    Plds[w][quad * 4 + r][lrow]      = (__bf16)pA;
                    Plds[w][quad * 4 + r][lrow + 16] = (__bf16)pB;
                }
            } else {
                #pragma unroll
                for (int r = 0; r < 4; ++r) {
                    float pA = exp2f(fmaf(s0[r], KSc, KOc));
                    float pB = exp2f(fmaf(s1[r], KSc, KOc));
                    lsum[r] += pA + pB;
                    Plds[w][quad * 4 + r][lrow]      = (__bf16)pA;
                    Plds[w][quad * 4 + r][lrow + 16] = (__bf16)pB;
                }
            }

            // V fragments: elem ((s*4+quad)*64 + c*16 + lrow)*8
            bf16x8 vf0 = *(const bf16x8*)&Vs[bb][((s * 4 + quad) * 64 +  0 + lrow) * 8];
            bf16x8 vf1 = *(const bf16x8*)&Vs[bb][((s * 4 + quad) * 64 + 16 + lrow) * 8];
            bf16x8 vf2 = *(const bf16x8*)&Vs[bb][((s * 4 + quad) * 64 + 32 + lrow) * 8];
            bf16x8 vf3 = *(const bf16x8*)&Vs[bb][((s * 4 + quad) * 64 + 48 + lrow) * 8];

            bf16x8 pf = *(const bf16x8*)&Plds[w][lrow][quad * 8];
            oacc[0] = __builtin_amdgcn_mfma_f32_16x16x32_bf16(pf, vf0, oacc[0], 0, 0, 0);
            oacc[1] = __builtin_amdgcn_mfma_f32_16x16x32_bf16(pf, vf1, oacc[1], 0, 0, 0);
            oacc[2] = __builtin_amdgcn_mfma_f32_16x16x32_bf16(pf, vf2, oacc[2], 0, 0, 0);
            oacc[3] = __builtin_amdgcn_mfma_f32_16x16x32_bf16(pf, vf3, oacc[3], 0, 0, 0);
        }
    }

    #pragma unroll
    for (int r = 0; r < 4; ++r) {
        float s = lsum[r];
        s += __shfl_xor(s, 1, 64);
        s += __shfl_xor(s, 2, 64);
        s += __shfl_xor(s, 4, 64);
        s += __shfl_xor(s, 8, 64);
        lsum[r] = 1.0f / s;
    }

    // O (bf16, [4096][1024], col = h*64 + dim); C-layout row=quad*4+r
    #pragma unroll
    for (int c = 0; c < 4; ++c)
        #pragma unroll
        for (int r = 0; r < 4; ++r) {
            const int i = i0 + quad * 4 + r;
            o[(size_t)(b * N_ + i) * D_ + h * HD_ + c * 16 + lrow] =
                (__bf16)(oacc[c][r] * lsum[r]);
        }
}

// ---------------------------------------------------------------------------
extern "C" void kernel_launch(void* const* d_in, const int* in_sizes, int n_in,
                              void* d_out, int out_size, void* d_ws, size_t ws_size,
                              hipStream_t stream)
{
    const float* x   = (const float*)d_in[0];
    const float* cs  = (const float*)d_in[1];
    const float* sn  = (const float*)d_in[2];
    const float* Wq  = (const float*)d_in[3];
    const float* Wk  = (const float*)d_in[4];
    const float* Wv  = (const float*)d_in[5];
    const float* Woe = (const float*)d_in[6];
    const float* Wod = (const float*)d_in[7];

    float* enc_out = (float*)d_out;
    float* dec_out = enc_out + (size_t)M_ * D_;

    // Workspace (57 MB), stream-ordered aliasing:
    //   [0,8)    xbf      -> reused as vtbf after QKV GEMM
    //   [8,14)   wqkv_t   (3072 x 1024 bf16)
    //   [14,16)  woe_t    (1024 x 1024 bf16)
    //   [16,17)  wod_t    (1024 x 512 bf16)
    //   [17,41)  qkv      (4096 x 3072 bf16) -> reused as obuf
    //   [41,49)  qbf head-major
    //   [49,57)  kbf head-major
    char* ws = (char*)d_ws;
    __bf16* xbf    = (__bf16*)(ws);
    __bf16* wqkv_t = (__bf16*)(ws + MB(8));
    __bf16* woe_t  = (__bf16*)(ws + MB(14));
    __bf16* wod_t  = (__bf16*)(ws + MB(16));
    __bf16* qkv    = (__bf16*)(ws + MB(17));
    __bf16* qbf    = (__bf16*)(ws + MB(41));
    __bf16* kbf    = (__bf16*)(ws + MB(49));
    __bf16* vtbf   = xbf;     // xbf dead after QKV GEMM
    __bf16* obuf   = qkv;     // qkv dead after rope_vconv

    // x convert
    f32_to_bf16<<<(M_ * D_) / (256 * 8), 256, 0, stream>>>(x, xbf);

    // all weight converts in one launch
    WtArgs wa;
    wa.W[0] = Wq;  wa.Wt[0] = wqkv_t;                 wa.K[0] = 1024; wa.nyb[0] = 16;
    wa.W[1] = Wk;  wa.Wt[1] = wqkv_t + 1024 * 1024;   wa.K[1] = 1024; wa.nyb[1] = 16;
    wa.W[2] = Wv;  wa.Wt[2] = wqkv_t + 2048 * 1024;   wa.K[2] = 1024; wa.nyb[2] = 16;
    wa.W[3] = Woe; wa.Wt[3] = woe_t;                  wa.K[3] = 1024; wa.nyb[3] = 16;
    wa.W[4] = Wod; wa.Wt[4] = wod_t;                  wa.K[4] = 512;  wa.nyb[4] = 8;
    wt_conv_all<<<dim3(16, 16, 5), 256, 0, stream>>>(wa);

    // Fused QKV projection (bf16 out)
    gemm_qkv<<<dim3(3072 / 128, M_ / 128), 256, 0, stream>>>(xbf, wqkv_t, qkv);

    // RoPE+RMSNorm + V transpose, one launch
    rope_vconv<<<16384 + 1024, 256, 0, stream>>>(qkv, cs, sn, qbf, kbf, vtbf);

    // Attention (32 bh x 32 q-blocks, heavy-first inside kernel)
    attn_mfma<<<dim3(B_ * H_, N_ / 64), 256, 0, stream>>>(qbf, kbf, vtbf, obuf);

    // Merged output projections (fp32 out)
    gemm_out<<<dim3(16, M_ / 128), 256, 0, stream>>>(
        obuf, woe_t, wod_t, enc_out, dec_out);
}